// Round 3
// baseline (982.971 us; speedup 1.0000x reference)
//
#include <hip/hip_runtime.h>
#include <math.h>

#define FDIM 128
#define RPB 128  // rows per bucket in the CSR counting sort (bucket = row >> 7)

// ---------------- CSR build ----------------

__global__ __launch_bounds__(256) void k_init(int* rowCnt, int* colCnt, int n) {
    int i = blockIdx.x * 256 + threadIdx.x;
    if (i < n) { rowCnt[i] = 0; colCnt[i] = 0; }
}

__global__ __launch_bounds__(256) void k_hist(const int* __restrict__ row, const int* __restrict__ col,
                                              int* rowCnt, int* colCnt, int nE) {
    int e = blockIdx.x * 256 + threadIdx.x;
    if (e < nE) {
        atomicAdd(&rowCnt[row[e]], 1);
        atomicAdd(&colCnt[col[e]], 1);
    }
}

__global__ __launch_bounds__(256) void k_dinv(const int* __restrict__ colCnt, float* dinv, int n) {
    int i = blockIdx.x * 256 + threadIdx.x;
    if (i < n) dinv[i] = 1.0f / sqrtf((float)colCnt[i] + 1.0f);
}

// inclusive scan of 256-element chunks
__global__ __launch_bounds__(256) void k_scan1(const int* __restrict__ cnt, int* chunkScan,
                                               int* partials, int n) {
    __shared__ int s[256];
    int tid = threadIdx.x;
    int i = blockIdx.x * 256 + tid;
    int v = (i < n) ? cnt[i] : 0;
    s[tid] = v;
    __syncthreads();
    for (int off = 1; off < 256; off <<= 1) {
        int t = (tid >= off) ? s[tid - off] : 0;
        __syncthreads();
        s[tid] += t;
        __syncthreads();
    }
    if (i < n) chunkScan[i] = s[tid];
    if (tid == 255) partials[blockIdx.x] = s[255];
}

// exclusive scan of block partials (nb <= 512), in place
__global__ __launch_bounds__(512) void k_scan2(int* partials, int nb) {
    __shared__ int s[512];
    int tid = threadIdx.x;
    int v = (tid < nb) ? partials[tid] : 0;
    s[tid] = v;
    __syncthreads();
    for (int off = 1; off < 512; off <<= 1) {
        int t = (tid >= off) ? s[tid - off] : 0;
        __syncthreads();
        s[tid] += t;
        __syncthreads();
    }
    if (tid < nb) partials[tid] = s[tid] - v;
}

__global__ __launch_bounds__(256) void k_scan3(const int* __restrict__ chunkScan,
                                               const int* __restrict__ partials,
                                               int* row_ptr, int n) {
    int i = blockIdx.x * 256 + threadIdx.x;
    if (i < n) row_ptr[i + 1] = chunkScan[i] + partials[blockIdx.x];
    if (i == 0) row_ptr[0] = 0;
}

// bucket cursors = CSR offset of each bucket's first row
__global__ __launch_bounds__(256) void k_binit(const int* __restrict__ row_ptr, int* bcur, int nb) {
    int b = blockIdx.x * 256 + threadIdx.x;
    if (b < nb) bcur[b] = row_ptr[b * RPB];
}

// Phase 1: scatter edges into row-range buckets. Writes advance ~nb sequential
// frontiers (L2-resident line set) instead of random lines over the whole CSR.
// Payload packed to 4B: (row & 127) << 25 | col   (needs col < 2^25).
__global__ __launch_bounds__(256) void k_bucket(const int* __restrict__ row, const int* __restrict__ col,
                                                int* bcur, unsigned int* __restrict__ pairs, int nE) {
    int e = blockIdx.x * 256 + threadIdx.x;
    if (e < nE) {
        int r = row[e];
        int c = col[e];
        int b = r >> 7;
        int pos = atomicAdd(&bcur[b], 1);
        pairs[pos] = ((unsigned int)(r & (RPB - 1)) << 25) | (unsigned int)c;
    }
}

// Phase 2: one workgroup per bucket; LDS per-row cursors; final csr_col writes
// land inside the bucket's contiguous CSR window (~full-line fills).
__global__ __launch_bounds__(256) void k_binsort(const int* __restrict__ row_ptr,
                                                 const unsigned int* __restrict__ pairs,
                                                 int* __restrict__ csr_col, int n) {
    __shared__ int lcur[RPB];
    const int b = blockIdx.x;
    const int row0 = b * RPB;
    const int rend = (row0 + RPB < n) ? (row0 + RPB) : n;
    const int tid = threadIdx.x;
    if (tid < RPB) {
        int r = row0 + tid;
        lcur[tid] = (r < n) ? row_ptr[r] : 0;
    }
    __syncthreads();
    const int start = row_ptr[row0];
    const int endp = row_ptr[rend];
    for (int i = start + tid; i < endp; i += 256) {
        unsigned int u = pairs[i];
        int lr = (int)(u >> 25);
        int c = (int)(u & 0x1FFFFFFu);
        int pos = atomicAdd(&lcur[lr], 1);
        csr_col[pos] = c;
    }
}

// ---------------- GEMM: out[r][c] = (sum_k X[r][k]*W[k][c] + bias[c]) * dinv[r] ----------------
// 64 rows x 128 cols per block, 256 threads, 4x8 acc per thread, k-tile 32.

__global__ __launch_bounds__(256) void k_gemm(const float* __restrict__ X, const float* __restrict__ W,
                                              const float* __restrict__ bias, const float* __restrict__ dinv,
                                              float* __restrict__ out, int nRows) {
    __shared__ float sX[32][68];   // [k][row], padded
    __shared__ float sW[32][132];  // [k][col], padded

    const int tid = threadIdx.x;
    const int row0 = blockIdx.x * 64;
    const int rb = (tid >> 4) * 4;   // 0..60
    const int cb = (tid & 15) * 8;   // 0..120

    float acc[4][8];
#pragma unroll
    for (int i = 0; i < 4; i++)
#pragma unroll
        for (int j = 0; j < 8; j++) acc[i][j] = 0.0f;

    for (int k0 = 0; k0 < FDIM; k0 += 32) {
#pragma unroll
        for (int it = 0; it < 2; it++) {
            int f = tid + it * 256;
            int r = f >> 3;
            int kq = (f & 7) * 4;
            float4 v = make_float4(0.f, 0.f, 0.f, 0.f);
            int gr = row0 + r;
            if (gr < nRows) v = *(const float4*)&X[(size_t)gr * FDIM + k0 + kq];
            sX[kq + 0][r] = v.x;
            sX[kq + 1][r] = v.y;
            sX[kq + 2][r] = v.z;
            sX[kq + 3][r] = v.w;
        }
#pragma unroll
        for (int it = 0; it < 4; it++) {
            int f = tid + it * 256;
            int k = f >> 5;
            int cq = (f & 31) * 4;
            float4 v = *(const float4*)&W[(size_t)(k0 + k) * FDIM + cq];
            *(float4*)&sW[k][cq] = v;
        }
        __syncthreads();
#pragma unroll 4
        for (int kk = 0; kk < 32; kk++) {
            float4 xv = *(const float4*)&sX[kk][rb];
            float wv[8];
            *(float4*)&wv[0] = *(const float4*)&sW[kk][cb];
            *(float4*)&wv[4] = *(const float4*)&sW[kk][cb + 4];
            float xs[4] = {xv.x, xv.y, xv.z, xv.w};
#pragma unroll
            for (int i = 0; i < 4; i++)
#pragma unroll
                for (int j = 0; j < 8; j++) acc[i][j] += xs[i] * wv[j];
        }
        __syncthreads();
    }

    float bv[8];
    *(float4*)&bv[0] = *(const float4*)&bias[cb];
    *(float4*)&bv[4] = *(const float4*)&bias[cb + 4];

#pragma unroll
    for (int i = 0; i < 4; i++) {
        int gr = row0 + rb + i;
        if (gr < nRows) {
            float di = dinv[gr];
            float4 o0, o1;
            o0.x = (acc[i][0] + bv[0]) * di;
            o0.y = (acc[i][1] + bv[1]) * di;
            o0.z = (acc[i][2] + bv[2]) * di;
            o0.w = (acc[i][3] + bv[3]) * di;
            o1.x = (acc[i][4] + bv[4]) * di;
            o1.y = (acc[i][5] + bv[5]) * di;
            o1.z = (acc[i][6] + bv[6]) * di;
            o1.w = (acc[i][7] + bv[7]) * di;
            *(float4*)&out[(size_t)gr * FDIM + cb] = o0;
            *(float4*)&out[(size_t)gr * FDIM + cb + 4] = o1;
        }
    }
}

// ---------------- Aggregation: out[i] = dinv[i]*(hs[i] + sum_{e in row i} hs[col[e]]) ----------------
// One wave per node. Lane-parallel index preload (64 edges per coalesced load),
// readlane broadcast -> SGPR-based gathers, 8 gathers in flight.

__global__ __launch_bounds__(256) void k_agg(const float* __restrict__ hs, const int* __restrict__ row_ptr,
                                             const int* __restrict__ csr_col, const float* __restrict__ dinv,
                                             float* __restrict__ out, int n, int relu) {
    int w = (blockIdx.x * 256 + threadIdx.x) >> 6;
    int lane = threadIdx.x & 63;
    if (w >= n) return;
    const float2* hs2 = (const float2*)hs;
    float2 v = hs2[(size_t)w * 64 + lane];
    float a0 = v.x, a1 = v.y;

    int e = row_ptr[w];
    const int end = row_ptr[w + 1];

    while (e < end) {
        int cnt = end - e;
        if (cnt > 64) cnt = 64;
        int jv = (e + lane < end) ? csr_col[e + lane] : 0;
        int t = 0;
        for (; t + 8 <= cnt; t += 8) {
            int j0 = __shfl(jv, t + 0, 64);
            int j1 = __shfl(jv, t + 1, 64);
            int j2 = __shfl(jv, t + 2, 64);
            int j3 = __shfl(jv, t + 3, 64);
            int j4 = __shfl(jv, t + 4, 64);
            int j5 = __shfl(jv, t + 5, 64);
            int j6 = __shfl(jv, t + 6, 64);
            int j7 = __shfl(jv, t + 7, 64);
            float2 u0 = hs2[(size_t)j0 * 64 + lane];
            float2 u1 = hs2[(size_t)j1 * 64 + lane];
            float2 u2 = hs2[(size_t)j2 * 64 + lane];
            float2 u3 = hs2[(size_t)j3 * 64 + lane];
            float2 u4 = hs2[(size_t)j4 * 64 + lane];
            float2 u5 = hs2[(size_t)j5 * 64 + lane];
            float2 u6 = hs2[(size_t)j6 * 64 + lane];
            float2 u7 = hs2[(size_t)j7 * 64 + lane];
            a0 += ((u0.x + u1.x) + (u2.x + u3.x)) + ((u4.x + u5.x) + (u6.x + u7.x));
            a1 += ((u0.y + u1.y) + (u2.y + u3.y)) + ((u4.y + u5.y) + (u6.y + u7.y));
        }
        for (; t < cnt; t++) {
            int j = __shfl(jv, t, 64);
            float2 u = hs2[(size_t)j * 64 + lane];
            a0 += u.x;
            a1 += u.y;
        }
        e += cnt;
    }

    float di = dinv[w];
    a0 *= di;
    a1 *= di;
    if (relu) {
        a0 = fmaxf(a0, 0.0f);
        a1 = fmaxf(a1, 0.0f);
    }
    ((float2*)out)[(size_t)w * 64 + lane] = make_float2(a0, a1);
}

// ---------------- log_softmax (in place), one wave per row ----------------

__global__ __launch_bounds__(256) void k_lsm(float* data, int n) {
    int w = (blockIdx.x * 256 + threadIdx.x) >> 6;
    int lane = threadIdx.x & 63;
    if (w >= n) return;
    float2* p = (float2*)data;
    float2 v = p[(size_t)w * 64 + lane];
    float m = fmaxf(v.x, v.y);
#pragma unroll
    for (int off = 32; off > 0; off >>= 1) m = fmaxf(m, __shfl_xor(m, off, 64));
    float s = expf(v.x - m) + expf(v.y - m);
#pragma unroll
    for (int off = 32; off > 0; off >>= 1) s += __shfl_xor(s, off, 64);
    float lg = m + logf(s);
    p[(size_t)w * 64 + lane] = make_float2(v.x - lg, v.y - lg);
}

// ---------------- launch ----------------

extern "C" void kernel_launch(void* const* d_in, const int* in_sizes, int n_in,
                              void* d_out, int out_size, void* d_ws, size_t ws_size,
                              hipStream_t stream) {
    const float* x  = (const float*)d_in[0];
    const float* W0 = (const float*)d_in[1];
    const float* b0 = (const float*)d_in[2];
    const float* W1 = (const float*)d_in[3];
    const float* b1 = (const float*)d_in[4];
    const int* row  = (const int*)d_in[5];
    const int* col  = (const int*)d_in[6];
    float* out = (float*)d_out;

    const int N = in_sizes[0] / FDIM;
    const int E = in_sizes[5];
    const int NB = (N + RPB - 1) / RPB;  // buckets

    char* w = (char*)d_ws;
    size_t off = 0;
    auto alloc = [&](size_t bytes) {
        char* p = w + off;
        off += (bytes + 255) & ~(size_t)255;
        return p;
    };
    int* rowCnt    = (int*)alloc((size_t)N * 4);
    int* colCnt    = (int*)alloc((size_t)N * 4);
    float* dinv    = (float*)alloc((size_t)N * 4);
    int* row_ptr   = (int*)alloc((size_t)(N + 1) * 4);
    int* chunkScan = (int*)alloc((size_t)N * 4);
    int* partials  = (int*)alloc(4096);
    int* bcur      = (int*)alloc((size_t)NB * 4);
    int* csr_col   = (int*)alloc((size_t)E * 4);
    float* bufA    = (float*)alloc((size_t)N * FDIM * 4);
    // pairs aliases bufA: CSR build finishes before the first GEMM writes bufA
    unsigned int* pairs = (unsigned int*)bufA;

    const int gN = (N + 255) / 256;       // node-grid
    const int gE = (E + 255) / 256;       // edge-grid
    const int gW = (N * 64 + 255) / 256;  // wave-per-node grid
    const int gG = (N + 63) / 64;         // gemm grid
    const int gB = (NB + 255) / 256;      // bucket-grid

    // CSR build + dinv
    k_init<<<gN, 256, 0, stream>>>(rowCnt, colCnt, N);
    k_hist<<<gE, 256, 0, stream>>>(row, col, rowCnt, colCnt, E);
    k_dinv<<<gN, 256, 0, stream>>>(colCnt, dinv, N);
    k_scan1<<<gN, 256, 0, stream>>>(rowCnt, chunkScan, partials, N);
    k_scan2<<<1, 512, 0, stream>>>(partials, gN);
    k_scan3<<<gN, 256, 0, stream>>>(chunkScan, partials, row_ptr, N);
    k_binit<<<gB, 256, 0, stream>>>(row_ptr, bcur, NB);
    k_bucket<<<gE, 256, 0, stream>>>(row, col, bcur, pairs, E);
    k_binsort<<<NB, 256, 0, stream>>>(row_ptr, pairs, csr_col, N);

    // layer 0: hs0 = (x@W0 + b0)*dinv  -> bufA ; agg -> d_out (with relu)
    k_gemm<<<gG, 256, 0, stream>>>(x, W0, b0, dinv, bufA, N);
    k_agg<<<gW, 256, 0, stream>>>(bufA, row_ptr, csr_col, dinv, out, N, 1);

    // layer 1: hs1 = (out@W1 + b1)*dinv -> bufA ; agg -> d_out (no relu)
    k_gemm<<<gG, 256, 0, stream>>>(out, W1, b1, dinv, bufA, N);
    k_agg<<<gW, 256, 0, stream>>>(bufA, row_ptr, csr_col, dinv, out, N, 0);

    // log_softmax in place on d_out
    k_lsm<<<gW, 256, 0, stream>>>(out, N);
}

// Round 4
// 699.309 us; speedup vs baseline: 1.4056x; 1.4056x over previous
//
#include <hip/hip_runtime.h>
#include <math.h>

#define FDIM 128
#define RPB 128      // rows per bucket in the CSR counting sort (bucket = row >> 7)
#define BSTRIDE 32   // ints per bucket cursor (128 B) — one cache line per counter

// ---------------- CSR build ----------------

__global__ __launch_bounds__(256) void k_init(int* rowCnt, int* colCnt, int n) {
    int i = blockIdx.x * 256 + threadIdx.x;
    if (i < n) { rowCnt[i] = 0; colCnt[i] = 0; }
}

__global__ __launch_bounds__(256) void k_hist(const int* __restrict__ row, const int* __restrict__ col,
                                              int* rowCnt, int* colCnt, int nE) {
    int e = blockIdx.x * 256 + threadIdx.x;
    if (e < nE) {
        atomicAdd(&rowCnt[row[e]], 1);
        atomicAdd(&colCnt[col[e]], 1);
    }
}

__global__ __launch_bounds__(256) void k_dinv(const int* __restrict__ colCnt, float* dinv, int n) {
    int i = blockIdx.x * 256 + threadIdx.x;
    if (i < n) dinv[i] = 1.0f / sqrtf((float)colCnt[i] + 1.0f);
}

// inclusive scan of 256-element chunks
__global__ __launch_bounds__(256) void k_scan1(const int* __restrict__ cnt, int* chunkScan,
                                               int* partials, int n) {
    __shared__ int s[256];
    int tid = threadIdx.x;
    int i = blockIdx.x * 256 + tid;
    int v = (i < n) ? cnt[i] : 0;
    s[tid] = v;
    __syncthreads();
    for (int off = 1; off < 256; off <<= 1) {
        int t = (tid >= off) ? s[tid - off] : 0;
        __syncthreads();
        s[tid] += t;
        __syncthreads();
    }
    if (i < n) chunkScan[i] = s[tid];
    if (tid == 255) partials[blockIdx.x] = s[255];
}

// exclusive scan of block partials (nb <= 512), in place
__global__ __launch_bounds__(512) void k_scan2(int* partials, int nb) {
    __shared__ int s[512];
    int tid = threadIdx.x;
    int v = (tid < nb) ? partials[tid] : 0;
    s[tid] = v;
    __syncthreads();
    for (int off = 1; off < 512; off <<= 1) {
        int t = (tid >= off) ? s[tid - off] : 0;
        __syncthreads();
        s[tid] += t;
        __syncthreads();
    }
    if (tid < nb) partials[tid] = s[tid] - v;
}

__global__ __launch_bounds__(256) void k_scan3(const int* __restrict__ chunkScan,
                                               const int* __restrict__ partials,
                                               int* row_ptr, int n) {
    int i = blockIdx.x * 256 + threadIdx.x;
    if (i < n) row_ptr[i + 1] = chunkScan[i] + partials[blockIdx.x];
    if (i == 0) row_ptr[0] = 0;
}

// bucket cursors = CSR offset of each bucket's first row; one per 128B line
__global__ __launch_bounds__(256) void k_binit(const int* __restrict__ row_ptr, int* bcur, int nb) {
    int b = blockIdx.x * 256 + threadIdx.x;
    if (b < nb) bcur[(size_t)b * BSTRIDE] = row_ptr[b * RPB];
}

// Phase 1: scatter edges into row-range buckets. Writes advance ~nb sequential
// frontiers; cursors padded to one cache line each to avoid atomic line contention.
// Payload packed to 4B: (row & 127) << 25 | col   (needs col < 2^25).
__global__ __launch_bounds__(256) void k_bucket(const int* __restrict__ row, const int* __restrict__ col,
                                                int* bcur, unsigned int* __restrict__ pairs, int nE) {
    int e = blockIdx.x * 256 + threadIdx.x;
    if (e < nE) {
        int r = row[e];
        int c = col[e];
        int b = r >> 7;
        int pos = atomicAdd(&bcur[(size_t)b * BSTRIDE], 1);
        pairs[pos] = ((unsigned int)(r & (RPB - 1)) << 25) | (unsigned int)c;
    }
}

// Phase 2: one workgroup per bucket; LDS per-row cursors; final csr_col writes
// land inside the bucket's contiguous CSR window (~full-line fills).
__global__ __launch_bounds__(256) void k_binsort(const int* __restrict__ row_ptr,
                                                 const unsigned int* __restrict__ pairs,
                                                 int* __restrict__ csr_col, int n) {
    __shared__ int lcur[RPB];
    const int b = blockIdx.x;
    const int row0 = b * RPB;
    const int rend = (row0 + RPB < n) ? (row0 + RPB) : n;
    const int tid = threadIdx.x;
    if (tid < RPB) {
        int r = row0 + tid;
        lcur[tid] = (r < n) ? row_ptr[r] : 0;
    }
    __syncthreads();
    const int start = row_ptr[row0];
    const int endp = row_ptr[rend];
    for (int i = start + tid; i < endp; i += 256) {
        unsigned int u = pairs[i];
        int lr = (int)(u >> 25);
        int c = (int)(u & 0x1FFFFFFu);
        int pos = atomicAdd(&lcur[lr], 1);
        csr_col[pos] = c;
    }
}

// ---------------- GEMM: out[r][c] = (sum_k X[r][k]*W[k][c] + bias[c]) * dinv[r] ----------------
// 64 rows x 128 cols per block, 256 threads, 4x8 acc per thread, k-tile 32.

__global__ __launch_bounds__(256) void k_gemm(const float* __restrict__ X, const float* __restrict__ W,
                                              const float* __restrict__ bias, const float* __restrict__ dinv,
                                              float* __restrict__ out, int nRows) {
    __shared__ float sX[32][68];   // [k][row], padded
    __shared__ float sW[32][132];  // [k][col], padded

    const int tid = threadIdx.x;
    const int row0 = blockIdx.x * 64;
    const int rb = (tid >> 4) * 4;   // 0..60
    const int cb = (tid & 15) * 8;   // 0..120

    float acc[4][8];
#pragma unroll
    for (int i = 0; i < 4; i++)
#pragma unroll
        for (int j = 0; j < 8; j++) acc[i][j] = 0.0f;

    for (int k0 = 0; k0 < FDIM; k0 += 32) {
#pragma unroll
        for (int it = 0; it < 2; it++) {
            int f = tid + it * 256;
            int r = f >> 3;
            int kq = (f & 7) * 4;
            float4 v = make_float4(0.f, 0.f, 0.f, 0.f);
            int gr = row0 + r;
            if (gr < nRows) v = *(const float4*)&X[(size_t)gr * FDIM + k0 + kq];
            sX[kq + 0][r] = v.x;
            sX[kq + 1][r] = v.y;
            sX[kq + 2][r] = v.z;
            sX[kq + 3][r] = v.w;
        }
#pragma unroll
        for (int it = 0; it < 4; it++) {
            int f = tid + it * 256;
            int k = f >> 5;
            int cq = (f & 31) * 4;
            float4 v = *(const float4*)&W[(size_t)(k0 + k) * FDIM + cq];
            *(float4*)&sW[k][cq] = v;
        }
        __syncthreads();
#pragma unroll 4
        for (int kk = 0; kk < 32; kk++) {
            float4 xv = *(const float4*)&sX[kk][rb];
            float wv[8];
            *(float4*)&wv[0] = *(const float4*)&sW[kk][cb];
            *(float4*)&wv[4] = *(const float4*)&sW[kk][cb + 4];
            float xs[4] = {xv.x, xv.y, xv.z, xv.w};
#pragma unroll
            for (int i = 0; i < 4; i++)
#pragma unroll
                for (int j = 0; j < 8; j++) acc[i][j] += xs[i] * wv[j];
        }
        __syncthreads();
    }

    float bv[8];
    *(float4*)&bv[0] = *(const float4*)&bias[cb];
    *(float4*)&bv[4] = *(const float4*)&bias[cb + 4];

#pragma unroll
    for (int i = 0; i < 4; i++) {
        int gr = row0 + rb + i;
        if (gr < nRows) {
            float di = dinv[gr];
            float4 o0, o1;
            o0.x = (acc[i][0] + bv[0]) * di;
            o0.y = (acc[i][1] + bv[1]) * di;
            o0.z = (acc[i][2] + bv[2]) * di;
            o0.w = (acc[i][3] + bv[3]) * di;
            o1.x = (acc[i][4] + bv[4]) * di;
            o1.y = (acc[i][5] + bv[5]) * di;
            o1.z = (acc[i][6] + bv[6]) * di;
            o1.w = (acc[i][7] + bv[7]) * di;
            *(float4*)&out[(size_t)gr * FDIM + cb] = o0;
            *(float4*)&out[(size_t)gr * FDIM + cb + 4] = o1;
        }
    }
}

// ---------------- Aggregation: out[i] = dinv[i]*(hs[i] + sum_{e in row i} hs[col[e]]) ----------------
// One wave per node. Lane-parallel index preload (64 edges per coalesced load),
// readlane broadcast -> SGPR-based gathers, 8 gathers in flight.

__global__ __launch_bounds__(256) void k_agg(const float* __restrict__ hs, const int* __restrict__ row_ptr,
                                             const int* __restrict__ csr_col, const float* __restrict__ dinv,
                                             float* __restrict__ out, int n, int relu) {
    int w = (blockIdx.x * 256 + threadIdx.x) >> 6;
    int lane = threadIdx.x & 63;
    if (w >= n) return;
    const float2* hs2 = (const float2*)hs;
    float2 v = hs2[(size_t)w * 64 + lane];
    float a0 = v.x, a1 = v.y;

    int e = row_ptr[w];
    const int end = row_ptr[w + 1];

    while (e < end) {
        int cnt = end - e;
        if (cnt > 64) cnt = 64;
        int jv = (e + lane < end) ? csr_col[e + lane] : 0;
        int t = 0;
        for (; t + 8 <= cnt; t += 8) {
            int j0 = __shfl(jv, t + 0, 64);
            int j1 = __shfl(jv, t + 1, 64);
            int j2 = __shfl(jv, t + 2, 64);
            int j3 = __shfl(jv, t + 3, 64);
            int j4 = __shfl(jv, t + 4, 64);
            int j5 = __shfl(jv, t + 5, 64);
            int j6 = __shfl(jv, t + 6, 64);
            int j7 = __shfl(jv, t + 7, 64);
            float2 u0 = hs2[(size_t)j0 * 64 + lane];
            float2 u1 = hs2[(size_t)j1 * 64 + lane];
            float2 u2 = hs2[(size_t)j2 * 64 + lane];
            float2 u3 = hs2[(size_t)j3 * 64 + lane];
            float2 u4 = hs2[(size_t)j4 * 64 + lane];
            float2 u5 = hs2[(size_t)j5 * 64 + lane];
            float2 u6 = hs2[(size_t)j6 * 64 + lane];
            float2 u7 = hs2[(size_t)j7 * 64 + lane];
            a0 += ((u0.x + u1.x) + (u2.x + u3.x)) + ((u4.x + u5.x) + (u6.x + u7.x));
            a1 += ((u0.y + u1.y) + (u2.y + u3.y)) + ((u4.y + u5.y) + (u6.y + u7.y));
        }
        for (; t < cnt; t++) {
            int j = __shfl(jv, t, 64);
            float2 u = hs2[(size_t)j * 64 + lane];
            a0 += u.x;
            a1 += u.y;
        }
        e += cnt;
    }

    float di = dinv[w];
    a0 *= di;
    a1 *= di;
    if (relu) {
        a0 = fmaxf(a0, 0.0f);
        a1 = fmaxf(a1, 0.0f);
    }
    ((float2*)out)[(size_t)w * 64 + lane] = make_float2(a0, a1);
}

// ---------------- log_softmax (in place), one wave per row ----------------

__global__ __launch_bounds__(256) void k_lsm(float* data, int n) {
    int w = (blockIdx.x * 256 + threadIdx.x) >> 6;
    int lane = threadIdx.x & 63;
    if (w >= n) return;
    float2* p = (float2*)data;
    float2 v = p[(size_t)w * 64 + lane];
    float m = fmaxf(v.x, v.y);
#pragma unroll
    for (int off = 32; off > 0; off >>= 1) m = fmaxf(m, __shfl_xor(m, off, 64));
    float s = expf(v.x - m) + expf(v.y - m);
#pragma unroll
    for (int off = 32; off > 0; off >>= 1) s += __shfl_xor(s, off, 64);
    float lg = m + logf(s);
    p[(size_t)w * 64 + lane] = make_float2(v.x - lg, v.y - lg);
}

// ---------------- launch ----------------

extern "C" void kernel_launch(void* const* d_in, const int* in_sizes, int n_in,
                              void* d_out, int out_size, void* d_ws, size_t ws_size,
                              hipStream_t stream) {
    const float* x  = (const float*)d_in[0];
    const float* W0 = (const float*)d_in[1];
    const float* b0 = (const float*)d_in[2];
    const float* W1 = (const float*)d_in[3];
    const float* b1 = (const float*)d_in[4];
    const int* row  = (const int*)d_in[5];
    const int* col  = (const int*)d_in[6];
    float* out = (float*)d_out;

    const int N = in_sizes[0] / FDIM;
    const int E = in_sizes[5];
    const int NB = (N + RPB - 1) / RPB;  // buckets

    char* w = (char*)d_ws;
    size_t off = 0;
    auto alloc = [&](size_t bytes) {
        char* p = w + off;
        off += (bytes + 255) & ~(size_t)255;
        return p;
    };
    int* rowCnt    = (int*)alloc((size_t)N * 4);
    int* colCnt    = (int*)alloc((size_t)N * 4);
    float* dinv    = (float*)alloc((size_t)N * 4);
    int* row_ptr   = (int*)alloc((size_t)(N + 1) * 4);
    int* chunkScan = (int*)alloc((size_t)N * 4);
    int* partials  = (int*)alloc(4096);
    int* bcur      = (int*)alloc((size_t)NB * BSTRIDE * 4);  // 1 cursor per 128B line
    int* csr_col   = (int*)alloc((size_t)E * 4);
    float* bufA    = (float*)alloc((size_t)N * FDIM * 4);
    // pairs aliases bufA: CSR build finishes before the first GEMM writes bufA
    unsigned int* pairs = (unsigned int*)bufA;

    const int gN = (N + 255) / 256;       // node-grid
    const int gE = (E + 255) / 256;       // edge-grid
    const int gW = (N * 64 + 255) / 256;  // wave-per-node grid
    const int gG = (N + 63) / 64;         // gemm grid
    const int gB = (NB + 255) / 256;      // bucket-grid

    // CSR build + dinv
    k_init<<<gN, 256, 0, stream>>>(rowCnt, colCnt, N);
    k_hist<<<gE, 256, 0, stream>>>(row, col, rowCnt, colCnt, E);
    k_dinv<<<gN, 256, 0, stream>>>(colCnt, dinv, N);
    k_scan1<<<gN, 256, 0, stream>>>(rowCnt, chunkScan, partials, N);
    k_scan2<<<1, 512, 0, stream>>>(partials, gN);
    k_scan3<<<gN, 256, 0, stream>>>(chunkScan, partials, row_ptr, N);
    k_binit<<<gB, 256, 0, stream>>>(row_ptr, bcur, NB);
    k_bucket<<<gE, 256, 0, stream>>>(row, col, bcur, pairs, E);
    k_binsort<<<NB, 256, 0, stream>>>(row_ptr, pairs, csr_col, N);

    // layer 0: hs0 = (x@W0 + b0)*dinv  -> bufA ; agg -> d_out (with relu)
    k_gemm<<<gG, 256, 0, stream>>>(x, W0, b0, dinv, bufA, N);
    k_agg<<<gW, 256, 0, stream>>>(bufA, row_ptr, csr_col, dinv, out, N, 1);

    // layer 1: hs1 = (out@W1 + b1)*dinv -> bufA ; agg -> d_out (no relu)
    k_gemm<<<gG, 256, 0, stream>>>(out, W1, b1, dinv, bufA, N);
    k_agg<<<gW, 256, 0, stream>>>(bufA, row_ptr, csr_col, dinv, out, N, 0);

    // log_softmax in place on d_out
    k_lsm<<<gW, 256, 0, stream>>>(out, N);
}